// Round 15
// baseline (9190.368 us; speedup 1.0000x reference)
//
#include <hip/hip_runtime.h>
#include <hip/hip_bf16.h>
#include <stdint.h>

typedef __attribute__((ext_vector_type(8))) short s16x8;   // 8 bf16 (4 VGPRs)
typedef __attribute__((ext_vector_type(4))) float f32x4;
typedef unsigned short u16;
typedef unsigned int u32;
typedef unsigned long long u64;

#define FEAT 2048
#define HID  512
#define GATES 2048   // 4*HID
#define NB   16
#define NT   2048
#define NOUT 22
#define MROWS (NB*NT)   // 32768

// ---- workspace layout (bytes) ----
#define WS_FLAG 0L
#define WS_BIAS 4096L                      // [2][2048] f32 = 16384
#define WS_WF   (WS_BIAS + 16384L)         // W_hh fragment-ordered: 4 MiB
#define WS_WB   (WS_WF + 4194304L)         // [2][2048][2048] u16 = 16 MiB
#define WS_XB   (WS_WB + 16777216L)        // x as bf16 = 128 MiB
#define WS_XG   (WS_XB + 134217728L)       // [2][32768][2048] u16 = 256 MiB
#define WS_HB   (WS_XG + 268435456L)       // [2][2049][16][512] u16 = 67,141,632 B
#define HB_BYTES 67141632L
#define HB_LSTM_U64 (2049L*2048L)          // u64 per lstm
#define HB_SLAB_U64 2048L                  // u64 per (lstm,t) slab (16 KiB)

__device__ inline float b2f(u16 u){ u32 x = ((u32)u) << 16; return __builtin_bit_cast(float, x); }
__device__ inline u16 f2b(float f){
  u32 u = __builtin_bit_cast(u32, f);
  u32 r = (u + 0x7FFFu + ((u >> 16) & 1u)) >> 16;   // RNE
  return (u16)r;
}
__device__ inline float sigm(float x){ return __builtin_amdgcn_rcpf(1.f + __expf(-x)); }
__device__ inline float tanh_(float x){ return 1.f - 2.f*__builtin_amdgcn_rcpf(1.f + __expf(2.f*x)); }

// ---------------- dtype detector ----------------
__global__ void detect_dtype(const u32* __restrict__ x, int* __restrict__ flag){
  __shared__ int cs;
  if (threadIdx.x == 0) cs = 0;
  __syncthreads();
  int c = 0;
  for (int i = 0; i < 16; i++){
    u32 w = x[threadIdx.x*16 + i];
    u32 e = (w >> 7) & 0xFFu;
    if ((e >= 110u && e <= 134u) || ((w & 0xFFFFu) == 0u)) c++;
  }
  atomicAdd(&cs, c);
  __syncthreads();
  if (threadIdx.x == 0) *flag = (cs > 2048) ? 1 : 0;
}

// ---------------- fp32|bf16 -> bf16 conversion/copy ----------------
__global__ void cvt_bf16(const void* __restrict__ src, u16* __restrict__ dst,
                         long n8, const int* __restrict__ flag){
  const int isb = *flag;
  long stride = (long)gridDim.x * blockDim.x;
  for (long i = (long)blockIdx.x*blockDim.x + threadIdx.x; i < n8; i += stride){
    if (isb){
      ((int4*)dst)[i] = ((const int4*)src)[i];
    } else {
      const float4* s = (const float4*)src + 2*i;
      float4 a = s[0], b = s[1];
      s16x8 o;
      o[0]=(short)f2b(a.x); o[1]=(short)f2b(a.y); o[2]=(short)f2b(a.z); o[3]=(short)f2b(a.w);
      o[4]=(short)f2b(b.x); o[5]=(short)f2b(b.y); o[6]=(short)f2b(b.z); o[7]=(short)f2b(b.w);
      *(s16x8*)(dst + i*8) = o;
    }
  }
}

// ---------------- bias combine ----------------
__global__ void bias_sum(const void* bi0, const void* bh0, const void* bi1, const void* bh1,
                         float* __restrict__ out, const int* __restrict__ flag){
  const int isb = *flag;
  int i = blockIdx.x*256 + threadIdx.x;     // 0..4095
  int lstm = i >> 11, idx = i & 2047;
  const void* bi = lstm ? bi1 : bi0;
  const void* bh = lstm ? bh1 : bh0;
  float a = isb ? b2f(((const u16*)bi)[idx]) : ((const float*)bi)[idx];
  float b = isb ? b2f(((const u16*)bh)[idx]) : ((const float*)bh)[idx];
  out[i] = a + b;
}

// ---------------- W_hh -> MFMA B-fragment order ----------------
__global__ void reorder_w(const void* __restrict__ w0, const void* __restrict__ w1,
                          u16* __restrict__ wfr, const int* __restrict__ flag){
  const int isb = *flag;
  int t = blockIdx.x*256 + threadIdx.x;      // 0 .. 262143
  int l   = t & 63;
  int kk  = (t >> 6) & 15;
  int tau = (t >> 10) & 127;
  int lstm = t >> 17;
  int m = tau >> 5;                          // gate
  int w = tau & 31;
  int j = m*512 + w*16 + (l & 15);
  size_t sidx = (size_t)j*HID + kk*32 + (l >> 4)*8;
  const void* src = lstm ? w1 : w0;
  s16x8 o;
  if (isb){
    o = *(const s16x8*)((const u16*)src + sidx);
  } else {
    const float* s = (const float*)src + sidx;
#pragma unroll
    for (int e = 0; e < 8; e++) o[e] = (short)f2b(s[e]);
  }
  *(s16x8*)(wfr + ((((size_t)lstm*128 + tau)*16 + kk)*64 + l)*8) = o;
}

// ---------------- FUSED kernel: 64 lstm blocks + 8192 gemm blocks ----------
// blockIdx < 64: R13's proven lstm_rec (threads >=64 exit; Wl in LDS union),
//   PLUS per-step xg sentinel validation (xg poisoned 0xFFFF = -NaN bf16,
//   never produced by finite GEMM; rare bounded sc0 sc1 scalar re-poll).
// blockIdx >= 64: gemm_xg with (a) t-block-major tile order so xg[t] is
//   produced far ahead of the recurrence consumer, (b) C-writes as
//   global_store_short sc0 sc1 (write-through -> IC-coherent mid-kernel).
// No dispatch-order assumption can deadlock: gemm blocks never wait.
union FSmem {
  struct { u16 As[2][8192]; u16 Bs[2][8192]; } g;   // 64 KiB gemm staging
  s16x8 Wl[4][16][64];                              // 64 KiB lstm weights
};

__global__ __launch_bounds__(256,2) void fused_rec(const u16* __restrict__ wfr,
    const u16* __restrict__ xb, const u16* __restrict__ wb,
    const float* __restrict__ bias, u16* __restrict__ xg, u64* __restrict__ hb64){
  __shared__ FSmem sm;

  if (blockIdx.x >= 64){
    // ================= GEMM role =================
    const int gid = blockIdx.x - 64;          // 0..8191
    const int lstm = gid & 1;
    const int n0 = ((gid >> 1) & 15) * 128;
    const int y = gid >> 5;                   // 0..255, t-block-major
    const int b = y & 15;
    const int tblk = y >> 4;
    const int m0 = b*NT + tblk*128;
    const int tid = threadIdx.x;
    const int lane = tid & 63;
    const int wid = tid >> 6;
    const int wr = wid >> 1, wc = wid & 1;
    const u16* Bw = wb + (size_t)lstm * GATES * FEAT;

    f32x4 acc[4][4] = {};

    auto stage = [&](int buf, int kt){
      const int k0 = kt*64;
#pragma unroll
      for (int i = 0; i < 4; i++){
        int cc = tid + 256*i;
        int row = cc >> 3;
        int slot = cc & 7;
        int slotp = slot ^ (row & 7);
        const u16* ga = xb + (size_t)(m0+row)*FEAT + k0 + slotp*8;
        const u16* gb = Bw + (size_t)(n0+row)*FEAT + k0 + slotp*8;
        __builtin_amdgcn_global_load_lds((const __attribute__((address_space(1))) void*)ga,
            (__attribute__((address_space(3))) void*)&sm.g.As[buf][cc*8], 16, 0, 0);
        __builtin_amdgcn_global_load_lds((const __attribute__((address_space(1))) void*)gb,
            (__attribute__((address_space(3))) void*)&sm.g.Bs[buf][cc*8], 16, 0, 0);
      }
    };

    stage(0, 0);
    __syncthreads();
    for (int kt = 0; kt < 32; kt++){
      int buf = kt & 1;
      if (kt < 31) stage(buf^1, kt+1);
      const char* Ab = (const char*)&sm.g.As[buf][0];
      const char* Bb = (const char*)&sm.g.Bs[buf][0];
#pragma unroll
      for (int ks = 0; ks < 2; ks++){
        s16x8 af[4], bf[4];
#pragma unroll
        for (int mi = 0; mi < 4; mi++){
          int row = wr*64 + mi*16 + (lane & 15);
          int off = row*128 + ((ks*64 + ((lane>>4)*16)) ^ ((row & 7) << 4));
          af[mi] = *(const s16x8*)(Ab + off);
        }
#pragma unroll
        for (int ni = 0; ni < 4; ni++){
          int row = wc*64 + ni*16 + (lane & 15);
          int off = row*128 + ((ks*64 + ((lane>>4)*16)) ^ ((row & 7) << 4));
          bf[ni] = *(const s16x8*)(Bb + off);
        }
#pragma unroll
        for (int mi = 0; mi < 4; mi++)
#pragma unroll
          for (int ni = 0; ni < 4; ni++)
            acc[mi][ni] = __builtin_amdgcn_mfma_f32_16x16x32_bf16(af[mi], bf[ni], acc[mi][ni], 0, 0, 0);
      }
      __syncthreads();
    }

    u16* xgl = xg + (size_t)lstm * MROWS * GATES;
#pragma unroll
    for (int mi = 0; mi < 4; mi++){
#pragma unroll
      for (int ni = 0; ni < 4; ni++){
        int gcol = n0 + wc*64 + ni*16 + (lane & 15);
        float bv = bias[lstm*GATES + gcol];
#pragma unroll
        for (int r = 0; r < 4; r++){
          int grow = m0 + wr*64 + mi*16 + ((lane>>4)<<2) + r;
          u16 val = f2b(acc[mi][ni][r] + bv);
          u16* ad = &xgl[(size_t)grow*GATES + gcol];
          asm volatile("global_store_short %0, %1, off sc0 sc1"
                       :: "v"(ad), "v"((u32)val));
        }
      }
    }
    return;
  }

  // ================= LSTM role (R13-proven, + xg validation) =================
  if (threadIdx.x >= 64) return;
  const int lstm = blockIdx.x >> 5;
  const int w = blockIdx.x & 31;
  const int lane = threadIdx.x;              // 0..63
  const int n = lane & 15;
  const int g = lane >> 4;
  const int b0 = g * 4;

  u64* myslab = hb64 + (size_t)lstm * HB_LSTM_U64;
  const char* srcp = (const char*)myslab + (size_t)n*1024 + g*16;

  // ---- fill LDS with this WG's W B-fragments (once) ----
  {
    const s16x8* wfb = (const s16x8*)wfr;
#pragma unroll
    for (int tt = 0; tt < 4; tt++){
      const s16x8* wt = wfb + (((size_t)lstm*128 + (tt*32 + w))*16)*64 + lane;
#pragma unroll
      for (int kk = 0; kk < 16; kk++)
        sm.Wl[tt][kk][lane] = wt[kk*64];
    }
  }

  // xg bases: gate m, batch b0+r, col j = m*512 + w*16 + n
  const u16* xpb[4];
#pragma unroll
  for (int m = 0; m < 4; m++)
    xpb[m] = xg + (size_t)lstm*MROWS*GATES + (size_t)b0*NT*GATES + (m*512 + w*16 + n);

  u16 xv[4][4], xn_[4][4];
#pragma unroll
  for (int m = 0; m < 4; m++)
#pragma unroll
    for (int r = 0; r < 4; r++)
      xv[m][r] = xpb[m][(size_t)r*NT*GATES];

  float c[4] = {};

  for (int t = 0; t < NT; t++){
    // ---- prefetch next xg (overlaps poll; one-step lead > HBM latency) ----
    const size_t tno = (size_t)((t < NT-1) ? (t+1) : t) * GATES;
#pragma unroll
    for (int m = 0; m < 4; m++)
#pragma unroll
      for (int r = 0; r < 4; r++)
        xn_[m][r] = xpb[m][(size_t)r*NT*GATES + tno];

    // ---- poll h(t): 16x16B batched, one waitcnt per round ----
    int4 H0,H1,H2,H3,H4,H5,H6,H7,H8,H9,H10,H11,H12,H13,H14,H15;
    int retry = 0;
    for (;;){
      asm volatile(
        "global_load_dwordx4 %0,  %16, off sc0 sc1\n"
        "global_load_dwordx4 %1,  %16, off offset:64 sc0 sc1\n"
        "global_load_dwordx4 %2,  %16, off offset:128 sc0 sc1\n"
        "global_load_dwordx4 %3,  %16, off offset:192 sc0 sc1\n"
        "global_load_dwordx4 %4,  %16, off offset:256 sc0 sc1\n"
        "global_load_dwordx4 %5,  %16, off offset:320 sc0 sc1\n"
        "global_load_dwordx4 %6,  %16, off offset:384 sc0 sc1\n"
        "global_load_dwordx4 %7,  %16, off offset:448 sc0 sc1\n"
        "global_load_dwordx4 %8,  %16, off offset:512 sc0 sc1\n"
        "global_load_dwordx4 %9,  %16, off offset:576 sc0 sc1\n"
        "global_load_dwordx4 %10, %16, off offset:640 sc0 sc1\n"
        "global_load_dwordx4 %11, %16, off offset:704 sc0 sc1\n"
        "global_load_dwordx4 %12, %16, off offset:768 sc0 sc1\n"
        "global_load_dwordx4 %13, %16, off offset:832 sc0 sc1\n"
        "global_load_dwordx4 %14, %16, off offset:896 sc0 sc1\n"
        "global_load_dwordx4 %15, %16, off offset:960 sc0 sc1\n"
        "s_waitcnt vmcnt(0)"
        : "=v"(H0), "=v"(H1), "=v"(H2), "=v"(H3),
          "=v"(H4), "=v"(H5), "=v"(H6), "=v"(H7),
          "=v"(H8), "=v"(H9), "=v"(H10), "=v"(H11),
          "=v"(H12), "=v"(H13), "=v"(H14), "=v"(H15)
        : "v"(srcp));
      u32 bad = ((u32)H0.x == ~0u) | ((u32)H0.z == ~0u)
              | ((u32)H1.x == ~0u) | ((u32)H1.z == ~0u)
              | ((u32)H2.x == ~0u) | ((u32)H2.z == ~0u)
              | ((u32)H3.x == ~0u) | ((u32)H3.z == ~0u)
              | ((u32)H4.x == ~0u) | ((u32)H4.z == ~0u)
              | ((u32)H5.x == ~0u) | ((u32)H5.z == ~0u)
              | ((u32)H6.x == ~0u) | ((u32)H6.z == ~0u)
              | ((u32)H7.x == ~0u) | ((u32)H7.z == ~0u)
              | ((u32)H8.x == ~0u) | ((u32)H8.z == ~0u)
              | ((u32)H9.x == ~0u) | ((u32)H9.z == ~0u)
              | ((u32)H10.x == ~0u) | ((u32)H10.z == ~0u)
              | ((u32)H11.x == ~0u) | ((u32)H11.z == ~0u)
              | ((u32)H12.x == ~0u) | ((u32)H12.z == ~0u)
              | ((u32)H13.x == ~0u) | ((u32)H13.z == ~0u)
              | ((u32)H14.x == ~0u) | ((u32)H14.z == ~0u)
              | ((u32)H15.x == ~0u) | ((u32)H15.z == ~0u);
      if (!__any(bad)) break;
      retry++;
      if ((retry & 15) == 0){
        int4 F[16];
#pragma unroll
        for (int i = 0; i < 16; i++){
          u64 a = __hip_atomic_load((const u64*)(srcp + i*64),
                                    __ATOMIC_RELAXED, __HIP_MEMORY_SCOPE_AGENT);
          u64 b = __hip_atomic_load((const u64*)(srcp + i*64 + 8),
                                    __ATOMIC_RELAXED, __HIP_MEMORY_SCOPE_AGENT);
          F[i].x = (int)(u32)a; F[i].y = (int)(u32)(a >> 32);
          F[i].z = (int)(u32)b; F[i].w = (int)(u32)(b >> 32);
        }
        u32 bad2 = 0;
#pragma unroll
        for (int i = 0; i < 16; i++)
          bad2 |= ((u32)F[i].x == ~0u) | ((u32)F[i].z == ~0u);
        if (!__any(bad2)){
          H0=F[0]; H1=F[1]; H2=F[2]; H3=F[3]; H4=F[4]; H5=F[5]; H6=F[6]; H7=F[7];
          H8=F[8]; H9=F[9]; H10=F[10]; H11=F[11]; H12=F[12]; H13=F[13]; H14=F[14]; H15=F[15];
          break;
        }
      }
      if (retry > (1 << 15)) break;          // bail visibly (NaN), never hang
      if (retry > 8) __builtin_amdgcn_s_sleep(1);
    }

    // ---- validate xv (xg[t]); rare bounded re-poll vs concurrent gemm ----
    {
      u32 xbad = 0;
#pragma unroll
      for (int m = 0; m < 4; m++)
#pragma unroll
        for (int r = 0; r < 4; r++) xbad |= (xv[m][r] == (u16)0xFFFFu);
      if (__builtin_expect(__any(xbad), 0)){
#pragma unroll
        for (int m = 0; m < 4; m++)
#pragma unroll
          for (int r = 0; r < 4; r++){
            if (xv[m][r] == (u16)0xFFFFu){
              const u16* a = xpb[m] + (size_t)r*NT*GATES + (size_t)t*GATES;
              u32 v; int k = 0;
              do {
                asm volatile("global_load_ushort %0, %1, off sc0 sc1\n"
                             "s_waitcnt vmcnt(0)" : "=v"(v) : "v"(a));
              } while ((u16)v == (u16)0xFFFFu && ++k < (1 << 15));
              xv[m][r] = (u16)v;
            }
          }
      }
    }

    // ---- MFMA: 4 gate tiles x K=512, B-fragments from LDS ----
    f32x4 a0 = {}, a1 = {}, a2 = {}, a3 = {};
#define LMM(kk, HV) { s16x8 hf = __builtin_bit_cast(s16x8, HV); \
      a0 = __builtin_amdgcn_mfma_f32_16x16x32_bf16(hf, sm.Wl[0][kk][lane], a0, 0, 0, 0); \
      a1 = __builtin_amdgcn_mfma_f32_16x16x32_bf16(hf, sm.Wl[1][kk][lane], a1, 0, 0, 0); \
      a2 = __builtin_amdgcn_mfma_f32_16x16x32_bf16(hf, sm.Wl[2][kk][lane], a2, 0, 0, 0); \
      a3 = __builtin_amdgcn_mfma_f32_16x16x32_bf16(hf, sm.Wl[3][kk][lane], a3, 0, 0, 0); }
    LMM(0,H0) LMM(1,H1) LMM(2,H2) LMM(3,H3) LMM(4,H4) LMM(5,H5) LMM(6,H6) LMM(7,H7)
    LMM(8,H8) LMM(9,H9) LMM(10,H10) LMM(11,H11) LMM(12,H12) LMM(13,H13) LMM(14,H14) LMM(15,H15)
#undef LMM

    // ---- gates (all in-lane: lane holds i,f,g,o for hid=w*16+n, b=b0+r) ----
    u16 hob[4];
#pragma unroll
    for (int r = 0; r < 4; r++){
      float iv = a0[r] + b2f(xv[0][r]);
      float fv = a1[r] + b2f(xv[1][r]);
      float gv = a2[r] + b2f(xv[2][r]);
      float ov = a3[r] + b2f(xv[3][r]);
      float cn = sigm(fv)*c[r] + sigm(iv)*tanh_(gv);
      c[r] = cn;
      hob[r] = f2b(sigm(ov)*tanh_(cn));
    }

    // ---- pack 4 consecutive hids into u64; publish (R6/R13-proven path) ----
    u64* dst = myslab + (size_t)(t+1)*HB_SLAB_U64;
    const int base4 = lane & 60;
#pragma unroll
    for (int r = 0; r < 4; r++){
      int hh = (int)hob[r];
      int v0 = __shfl(hh, base4+0, 64) & 0xFFFF;
      int v1 = __shfl(hh, base4+1, 64) & 0xFFFF;
      int v2 = __shfl(hh, base4+2, 64) & 0xFFFF;
      int v3 = __shfl(hh, base4+3, 64) & 0xFFFF;
      u64 v = (u64)(u32)(v0 | (v1 << 16)) | ((u64)(u32)(v2 | (v3 << 16)) << 32);
      if ((lane & 3) == 0){
        u64* d = dst + (size_t)(b0 + r)*128 + (w*4 + (n >> 2));
        __hip_atomic_store(d, v, __ATOMIC_RELAXED, __HIP_MEMORY_SCOPE_AGENT);
      }
    }
#pragma unroll
    for (int m = 0; m < 4; m++)
#pragma unroll
      for (int r = 0; r < 4; r++) xv[m][r] = xn_[m][r];
    srcp += HB_SLAB_U64 * 8;
  }
}

// ---------------- linear heads: out = h @ fc_w^T + fc_b (reads hb[t+1]) ------
__global__ __launch_bounds__(256,4) void head_fc(const u16* __restrict__ hb,
    const void* fcw0, const void* fcb0, const void* fcw1, const void* fcb1,
    void* __restrict__ dout, const int* __restrict__ flag){
  const int isb = *flag;
  const int lane = threadIdx.x & 63;
  const int wv = threadIdx.x >> 6;
  int row = blockIdx.x*4 + wv;                 // lstm*32768 + b*2048 + t
  const int lstm = row >> 15;
  const int rem = row & 32767;
  const int b = rem >> 11;
  const int t = rem & 2047;
  const u16* hrow = hb + (((size_t)lstm*2049 + (t+1))*16 + b)*512;
  float hv[8];
  {
    s16x8 h8 = *(const s16x8*)(hrow + lane*8);
#pragma unroll
    for (int e = 0; e < 8; e++) hv[e] = b2f((u16)h8[e]);
  }
  const void* fcw = lstm ? fcw1 : fcw0;
  const void* fcb = lstm ? fcb1 : fcb0;
  float bval = 0.f;
  if (lane < NOUT) bval = isb ? b2f(((const u16*)fcb)[lane]) : ((const float*)fcb)[lane];
  float res = 0.f;
  for (int o = 0; o < NOUT; o++){
    float pa = 0.f;
    if (isb){
      s16x8 w8 = *(const s16x8*)((const u16*)fcw + (size_t)o*HID + lane*8);
#pragma unroll
      for (int e = 0; e < 8; e++) pa += hv[e] * b2f((u16)w8[e]);
    } else {
      const float* wr = (const float*)fcw + (size_t)o*HID + lane*8;
#pragma unroll
      for (int e = 0; e < 8; e++) pa += hv[e] * wr[e];
    }
#pragma unroll
    for (int d = 1; d < 64; d <<= 1) pa += __shfl_xor(pa, d, 64);
    if (lane == o) res = pa + bval;
  }
  size_t off = (size_t)lstm*(MROWS*NOUT) + (size_t)rem*NOUT;
  if (lane < NOUT){
    if (isb) ((u16*)dout)[off + lane] = f2b(res);
    else     ((float*)dout)[off + lane] = res;
  }
}

extern "C" void kernel_launch(void* const* d_in, const int* in_sizes, int n_in,
                              void* d_out, int out_size, void* d_ws, size_t ws_size,
                              hipStream_t stream){
  char* ws = (char*)d_ws;
  int*   flag = (int*)(ws + WS_FLAG);
  float* bias = (float*)(ws + WS_BIAS);
  u16*   wfr  = (u16*)(ws + WS_WF);
  u16*   wb   = (u16*)(ws + WS_WB);
  u16*   xb   = (u16*)(ws + WS_XB);
  u16*   xg   = (u16*)(ws + WS_XG);
  u16*   hb   = (u16*)(ws + WS_HB);

  (void)hipMemsetAsync(ws + WS_FLAG, 0, 4096, stream);
  // sentinel-fill h history, then zero the t=0 slabs (h(0)=0)
  (void)hipMemsetAsync(ws + WS_HB, 0xFF, HB_BYTES, stream);
  (void)hipMemsetAsync(ws + WS_HB, 0, 16384, stream);
  (void)hipMemsetAsync(ws + WS_HB + 2049L*16*512*2, 0, 16384, stream);
  // sentinel-fill xg (consumed by the fused recurrence with validation)
  (void)hipMemsetAsync(ws + WS_XG, 0xFF, 268435456L, stream);

  detect_dtype<<<1, 256, 0, stream>>>((const u32*)d_in[0], flag);

  cvt_bf16<<<2048, 256, 0, stream>>>(d_in[0], xb,             67108864L/8, flag); // x
  cvt_bf16<<<2048, 256, 0, stream>>>(d_in[1], wb,              4194304L/8, flag); // w_ih
  cvt_bf16<<<2048, 256, 0, stream>>>(d_in[5], wb + 4194304L,   4194304L/8, flag); // w_ih_ed
  reorder_w<<<1024, 256, 0, stream>>>(d_in[2], d_in[6], wfr, flag);               // w_hh both
  bias_sum<<<16, 256, 0, stream>>>(d_in[3], d_in[4], d_in[7], d_in[8], bias, flag);

  fused_rec<<<64 + 8192, 256, 0, stream>>>(wfr, xb, wb, bias, xg, (u64*)hb);
  head_fc<<<16384, 256, 0, stream>>>(hb, d_in[9], d_in[10], d_in[11], d_in[12], d_out, flag);
}

// Round 16
// 8985.022 us; speedup vs baseline: 1.0229x; 1.0229x over previous
//
#include <hip/hip_runtime.h>
#include <hip/hip_bf16.h>
#include <stdint.h>

typedef __attribute__((ext_vector_type(8))) short s16x8;   // 8 bf16 (4 VGPRs)
typedef __attribute__((ext_vector_type(4))) float f32x4;
typedef unsigned short u16;
typedef unsigned int u32;
typedef unsigned long long u64;

#define FEAT 2048
#define HID  512
#define GATES 2048   // 4*HID
#define NB   16
#define NT   2048
#define NOUT 22
#define MROWS (NB*NT)   // 32768

// ---- workspace layout (bytes) ----
#define WS_FLAG 0L
#define WS_BIAS 4096L                      // [2][2048] f32 = 16384
#define WS_WF   (WS_BIAS + 16384L)         // W_hh fragment-ordered: 4 MiB
#define WS_WB   (WS_WF + 4194304L)         // [2][2048][2048] u16 = 16 MiB
#define WS_XB   (WS_WB + 16777216L)        // x as bf16 = 128 MiB
#define WS_XG   (WS_XB + 134217728L)       // [2][32768][2048] u16 = 256 MiB
#define WS_HB   (WS_XG + 268435456L)       // [2][2049][16][512] u16 = 67,141,632 B
#define HB_BYTES 67141632L
#define HB_LSTM_U64 (2049L*2048L)          // u64 per lstm
#define HB_SLAB_U64 2048L                  // u64 per (lstm,t) slab (16 KiB)

__device__ inline float b2f(u16 u){ u32 x = ((u32)u) << 16; return __builtin_bit_cast(float, x); }
__device__ inline u16 f2b(float f){
  u32 u = __builtin_bit_cast(u32, f);
  u32 r = (u + 0x7FFFu + ((u >> 16) & 1u)) >> 16;   // RNE
  return (u16)r;
}
__device__ inline float sigm(float x){ return __builtin_amdgcn_rcpf(1.f + __expf(-x)); }
__device__ inline float tanh_(float x){ return 1.f - 2.f*__builtin_amdgcn_rcpf(1.f + __expf(2.f*x)); }

// ---------------- dtype detector ----------------
__global__ void detect_dtype(const u32* __restrict__ x, int* __restrict__ flag){
  __shared__ int cs;
  if (threadIdx.x == 0) cs = 0;
  __syncthreads();
  int c = 0;
  for (int i = 0; i < 16; i++){
    u32 w = x[threadIdx.x*16 + i];
    u32 e = (w >> 7) & 0xFFu;
    if ((e >= 110u && e <= 134u) || ((w & 0xFFFFu) == 0u)) c++;
  }
  atomicAdd(&cs, c);
  __syncthreads();
  if (threadIdx.x == 0) *flag = (cs > 2048) ? 1 : 0;
}

// ---------------- fp32|bf16 -> bf16 conversion/copy ----------------
__global__ void cvt_bf16(const void* __restrict__ src, u16* __restrict__ dst,
                         long n8, const int* __restrict__ flag){
  const int isb = *flag;
  long stride = (long)gridDim.x * blockDim.x;
  for (long i = (long)blockIdx.x*blockDim.x + threadIdx.x; i < n8; i += stride){
    if (isb){
      ((int4*)dst)[i] = ((const int4*)src)[i];
    } else {
      const float4* s = (const float4*)src + 2*i;
      float4 a = s[0], b = s[1];
      s16x8 o;
      o[0]=(short)f2b(a.x); o[1]=(short)f2b(a.y); o[2]=(short)f2b(a.z); o[3]=(short)f2b(a.w);
      o[4]=(short)f2b(b.x); o[5]=(short)f2b(b.y); o[6]=(short)f2b(b.z); o[7]=(short)f2b(b.w);
      *(s16x8*)(dst + i*8) = o;
    }
  }
}

// ---------------- bias combine ----------------
__global__ void bias_sum(const void* bi0, const void* bh0, const void* bi1, const void* bh1,
                         float* __restrict__ out, const int* __restrict__ flag){
  const int isb = *flag;
  int i = blockIdx.x*256 + threadIdx.x;     // 0..4095
  int lstm = i >> 11, idx = i & 2047;
  const void* bi = lstm ? bi1 : bi0;
  const void* bh = lstm ? bh1 : bh0;
  float a = isb ? b2f(((const u16*)bi)[idx]) : ((const float*)bi)[idx];
  float b = isb ? b2f(((const u16*)bh)[idx]) : ((const float*)bh)[idx];
  out[i] = a + b;
}

// ---------------- W_hh -> MFMA B-fragment order ----------------
__global__ void reorder_w(const void* __restrict__ w0, const void* __restrict__ w1,
                          u16* __restrict__ wfr, const int* __restrict__ flag){
  const int isb = *flag;
  int t = blockIdx.x*256 + threadIdx.x;      // 0 .. 262143
  int l   = t & 63;
  int kk  = (t >> 6) & 15;
  int tau = (t >> 10) & 127;
  int lstm = t >> 17;
  int m = tau >> 5;                          // gate
  int w = tau & 31;
  int j = m*512 + w*16 + (l & 15);
  size_t sidx = (size_t)j*HID + kk*32 + (l >> 4)*8;
  const void* src = lstm ? w1 : w0;
  s16x8 o;
  if (isb){
    o = *(const s16x8*)((const u16*)src + sidx);
  } else {
    const float* s = (const float*)src + sidx;
#pragma unroll
    for (int e = 0; e < 8; e++) o[e] = (short)f2b(s[e]);
  }
  *(s16x8*)(wfr + ((((size_t)lstm*128 + tau)*16 + kk)*64 + l)*8) = o;
}

// ---------------- FUSED kernel: 64 lstm blocks + 8192 gemm blocks ----------
// R15-identical except: FSmem padded to 100 KiB + launch_bounds(256,1) so NO
// two blocks co-reside on a CU (100+100 > 160 KiB). The 64 persistent lstm
// blocks own their CUs outright -- the gemm waves can no longer steal
// vector-memory issue slots during the latency-critical poll/publish window.
// gemm cycles through the remaining 192 CUs at occupancy 1 (~1 ms, hidden).
union FSmem {
  struct { u16 As[2][8192]; u16 Bs[2][8192]; } g;   // 64 KiB gemm staging
  s16x8 Wl[4][16][64];                              // 64 KiB lstm weights
  char pad[102400];                                 // force 100 KiB LDS/block
};

__global__ __launch_bounds__(256,1) void fused_rec(const u16* __restrict__ wfr,
    const u16* __restrict__ xb, const u16* __restrict__ wb,
    const float* __restrict__ bias, u16* __restrict__ xg, u64* __restrict__ hb64){
  __shared__ FSmem sm;

  if (blockIdx.x >= 64){
    // ================= GEMM role =================
    const int gid = blockIdx.x - 64;          // 0..8191
    const int lstm = gid & 1;
    const int n0 = ((gid >> 1) & 15) * 128;
    const int y = gid >> 5;                   // 0..255, t-block-major
    const int b = y & 15;
    const int tblk = y >> 4;
    const int m0 = b*NT + tblk*128;
    const int tid = threadIdx.x;
    const int lane = tid & 63;
    const int wid = tid >> 6;
    const int wr = wid >> 1, wc = wid & 1;
    const u16* Bw = wb + (size_t)lstm * GATES * FEAT;

    f32x4 acc[4][4] = {};

    auto stage = [&](int buf, int kt){
      const int k0 = kt*64;
#pragma unroll
      for (int i = 0; i < 4; i++){
        int cc = tid + 256*i;
        int row = cc >> 3;
        int slot = cc & 7;
        int slotp = slot ^ (row & 7);
        const u16* ga = xb + (size_t)(m0+row)*FEAT + k0 + slotp*8;
        const u16* gb = Bw + (size_t)(n0+row)*FEAT + k0 + slotp*8;
        __builtin_amdgcn_global_load_lds((const __attribute__((address_space(1))) void*)ga,
            (__attribute__((address_space(3))) void*)&sm.g.As[buf][cc*8], 16, 0, 0);
        __builtin_amdgcn_global_load_lds((const __attribute__((address_space(1))) void*)gb,
            (__attribute__((address_space(3))) void*)&sm.g.Bs[buf][cc*8], 16, 0, 0);
      }
    };

    stage(0, 0);
    __syncthreads();
    for (int kt = 0; kt < 32; kt++){
      int buf = kt & 1;
      if (kt < 31) stage(buf^1, kt+1);
      const char* Ab = (const char*)&sm.g.As[buf][0];
      const char* Bb = (const char*)&sm.g.Bs[buf][0];
#pragma unroll
      for (int ks = 0; ks < 2; ks++){
        s16x8 af[4], bf[4];
#pragma unroll
        for (int mi = 0; mi < 4; mi++){
          int row = wr*64 + mi*16 + (lane & 15);
          int off = row*128 + ((ks*64 + ((lane>>4)*16)) ^ ((row & 7) << 4));
          af[mi] = *(const s16x8*)(Ab + off);
        }
#pragma unroll
        for (int ni = 0; ni < 4; ni++){
          int row = wc*64 + ni*16 + (lane & 15);
          int off = row*128 + ((ks*64 + ((lane>>4)*16)) ^ ((row & 7) << 4));
          bf[ni] = *(const s16x8*)(Bb + off);
        }
#pragma unroll
        for (int mi = 0; mi < 4; mi++)
#pragma unroll
          for (int ni = 0; ni < 4; ni++)
            acc[mi][ni] = __builtin_amdgcn_mfma_f32_16x16x32_bf16(af[mi], bf[ni], acc[mi][ni], 0, 0, 0);
      }
      __syncthreads();
    }

    u16* xgl = xg + (size_t)lstm * MROWS * GATES;
#pragma unroll
    for (int mi = 0; mi < 4; mi++){
#pragma unroll
      for (int ni = 0; ni < 4; ni++){
        int gcol = n0 + wc*64 + ni*16 + (lane & 15);
        float bv = bias[lstm*GATES + gcol];
#pragma unroll
        for (int r = 0; r < 4; r++){
          int grow = m0 + wr*64 + mi*16 + ((lane>>4)<<2) + r;
          u16 val = f2b(acc[mi][ni][r] + bv);
          u16* ad = &xgl[(size_t)grow*GATES + gcol];
          asm volatile("global_store_short %0, %1, off sc0 sc1"
                       :: "v"(ad), "v"((u32)val));
        }
      }
    }
    return;
  }

  // ================= LSTM role (R13-proven, + xg validation) =================
  if (threadIdx.x >= 64) return;
  const int lstm = blockIdx.x >> 5;
  const int w = blockIdx.x & 31;
  const int lane = threadIdx.x;              // 0..63
  const int n = lane & 15;
  const int g = lane >> 4;
  const int b0 = g * 4;

  u64* myslab = hb64 + (size_t)lstm * HB_LSTM_U64;
  const char* srcp = (const char*)myslab + (size_t)n*1024 + g*16;

  // ---- fill LDS with this WG's W B-fragments (once) ----
  {
    const s16x8* wfb = (const s16x8*)wfr;
#pragma unroll
    for (int tt = 0; tt < 4; tt++){
      const s16x8* wt = wfb + (((size_t)lstm*128 + (tt*32 + w))*16)*64 + lane;
#pragma unroll
      for (int kk = 0; kk < 16; kk++)
        sm.Wl[tt][kk][lane] = wt[kk*64];
    }
  }

  // xg bases: gate m, batch b0+r, col j = m*512 + w*16 + n
  const u16* xpb[4];
#pragma unroll
  for (int m = 0; m < 4; m++)
    xpb[m] = xg + (size_t)lstm*MROWS*GATES + (size_t)b0*NT*GATES + (m*512 + w*16 + n);

  u16 xv[4][4], xn_[4][4];
#pragma unroll
  for (int m = 0; m < 4; m++)
#pragma unroll
    for (int r = 0; r < 4; r++)
      xv[m][r] = xpb[m][(size_t)r*NT*GATES];

  float c[4] = {};

  for (int t = 0; t < NT; t++){
    // ---- prefetch next xg (overlaps poll; one-step lead > HBM latency) ----
    const size_t tno = (size_t)((t < NT-1) ? (t+1) : t) * GATES;
#pragma unroll
    for (int m = 0; m < 4; m++)
#pragma unroll
      for (int r = 0; r < 4; r++)
        xn_[m][r] = xpb[m][(size_t)r*NT*GATES + tno];

    // ---- poll h(t): 16x16B batched, one waitcnt per round ----
    int4 H0,H1,H2,H3,H4,H5,H6,H7,H8,H9,H10,H11,H12,H13,H14,H15;
    int retry = 0;
    for (;;){
      asm volatile(
        "global_load_dwordx4 %0,  %16, off sc0 sc1\n"
        "global_load_dwordx4 %1,  %16, off offset:64 sc0 sc1\n"
        "global_load_dwordx4 %2,  %16, off offset:128 sc0 sc1\n"
        "global_load_dwordx4 %3,  %16, off offset:192 sc0 sc1\n"
        "global_load_dwordx4 %4,  %16, off offset:256 sc0 sc1\n"
        "global_load_dwordx4 %5,  %16, off offset:320 sc0 sc1\n"
        "global_load_dwordx4 %6,  %16, off offset:384 sc0 sc1\n"
        "global_load_dwordx4 %7,  %16, off offset:448 sc0 sc1\n"
        "global_load_dwordx4 %8,  %16, off offset:512 sc0 sc1\n"
        "global_load_dwordx4 %9,  %16, off offset:576 sc0 sc1\n"
        "global_load_dwordx4 %10, %16, off offset:640 sc0 sc1\n"
        "global_load_dwordx4 %11, %16, off offset:704 sc0 sc1\n"
        "global_load_dwordx4 %12, %16, off offset:768 sc0 sc1\n"
        "global_load_dwordx4 %13, %16, off offset:832 sc0 sc1\n"
        "global_load_dwordx4 %14, %16, off offset:896 sc0 sc1\n"
        "global_load_dwordx4 %15, %16, off offset:960 sc0 sc1\n"
        "s_waitcnt vmcnt(0)"
        : "=v"(H0), "=v"(H1), "=v"(H2), "=v"(H3),
          "=v"(H4), "=v"(H5), "=v"(H6), "=v"(H7),
          "=v"(H8), "=v"(H9), "=v"(H10), "=v"(H11),
          "=v"(H12), "=v"(H13), "=v"(H14), "=v"(H15)
        : "v"(srcp));
      u32 bad = ((u32)H0.x == ~0u) | ((u32)H0.z == ~0u)
              | ((u32)H1.x == ~0u) | ((u32)H1.z == ~0u)
              | ((u32)H2.x == ~0u) | ((u32)H2.z == ~0u)
              | ((u32)H3.x == ~0u) | ((u32)H3.z == ~0u)
              | ((u32)H4.x == ~0u) | ((u32)H4.z == ~0u)
              | ((u32)H5.x == ~0u) | ((u32)H5.z == ~0u)
              | ((u32)H6.x == ~0u) | ((u32)H6.z == ~0u)
              | ((u32)H7.x == ~0u) | ((u32)H7.z == ~0u)
              | ((u32)H8.x == ~0u) | ((u32)H8.z == ~0u)
              | ((u32)H9.x == ~0u) | ((u32)H9.z == ~0u)
              | ((u32)H10.x == ~0u) | ((u32)H10.z == ~0u)
              | ((u32)H11.x == ~0u) | ((u32)H11.z == ~0u)
              | ((u32)H12.x == ~0u) | ((u32)H12.z == ~0u)
              | ((u32)H13.x == ~0u) | ((u32)H13.z == ~0u)
              | ((u32)H14.x == ~0u) | ((u32)H14.z == ~0u)
              | ((u32)H15.x == ~0u) | ((u32)H15.z == ~0u);
      if (!__any(bad)) break;
      retry++;
      if ((retry & 15) == 0){
        int4 F[16];
#pragma unroll
        for (int i = 0; i < 16; i++){
          u64 a = __hip_atomic_load((const u64*)(srcp + i*64),
                                    __ATOMIC_RELAXED, __HIP_MEMORY_SCOPE_AGENT);
          u64 b = __hip_atomic_load((const u64*)(srcp + i*64 + 8),
                                    __ATOMIC_RELAXED, __HIP_MEMORY_SCOPE_AGENT);
          F[i].x = (int)(u32)a; F[i].y = (int)(u32)(a >> 32);
          F[i].z = (int)(u32)b; F[i].w = (int)(u32)(b >> 32);
        }
        u32 bad2 = 0;
#pragma unroll
        for (int i = 0; i < 16; i++)
          bad2 |= ((u32)F[i].x == ~0u) | ((u32)F[i].z == ~0u);
        if (!__any(bad2)){
          H0=F[0]; H1=F[1]; H2=F[2]; H3=F[3]; H4=F[4]; H5=F[5]; H6=F[6]; H7=F[7];
          H8=F[8]; H9=F[9]; H10=F[10]; H11=F[11]; H12=F[12]; H13=F[13]; H14=F[14]; H15=F[15];
          break;
        }
      }
      if (retry > (1 << 15)) break;          // bail visibly (NaN), never hang
      if (retry > 8) __builtin_amdgcn_s_sleep(1);
    }

    // ---- validate xv (xg[t]); rare bounded re-poll vs concurrent gemm ----
    {
      u32 xbad = 0;
#pragma unroll
      for (int m = 0; m < 4; m++)
#pragma unroll
        for (int r = 0; r < 4; r++) xbad |= (xv[m][r] == (u16)0xFFFFu);
      if (__builtin_expect(__any(xbad), 0)){
#pragma unroll
        for (int m = 0; m < 4; m++)
#pragma unroll
          for (int r = 0; r < 4; r++){
            if (xv[m][r] == (u16)0xFFFFu){
              const u16* a = xpb[m] + (size_t)r*NT*GATES + (size_t)t*GATES;
              u32 v; int k = 0;
              do {
                asm volatile("global_load_ushort %0, %1, off sc0 sc1\n"
                             "s_waitcnt vmcnt(0)" : "=v"(v) : "v"(a));
              } while ((u16)v == (u16)0xFFFFu && ++k < (1 << 15));
              xv[m][r] = (u16)v;
            }
          }
      }
    }

    // ---- MFMA: 4 gate tiles x K=512, B-fragments from LDS ----
    f32x4 a0 = {}, a1 = {}, a2 = {}, a3 = {};
#define LMM(kk, HV) { s16x8 hf = __builtin_bit_cast(s16x8, HV); \
      a0 = __builtin_amdgcn_mfma_f32_16x16x32_bf16(hf, sm.Wl[0][kk][lane], a0, 0, 0, 0); \
      a1 = __builtin_amdgcn_mfma_f32_16x16x32_bf16(hf, sm.Wl[1][kk][lane], a1, 0, 0, 0); \
      a2 = __builtin_amdgcn_mfma_f32_16x16x32_bf16(hf, sm.Wl[2][kk][lane], a2, 0, 0, 0); \
      a3 = __builtin_amdgcn_mfma_f32_16x16x32_bf16(hf, sm.Wl[3][kk][lane], a3, 0, 0, 0); }
    LMM(0,H0) LMM(1,H1) LMM(2,H2) LMM(3,H3) LMM(4,H4) LMM(5,H5) LMM(6,H6) LMM(7,H7)
    LMM(8,H8) LMM(9,H9) LMM(10,H10) LMM(11,H11) LMM(12,H12) LMM(13,H13) LMM(14,H14) LMM(15,H15)
#undef LMM

    // ---- gates (all in-lane: lane holds i,f,g,o for hid=w*16+n, b=b0+r) ----
    u16 hob[4];
#pragma unroll
    for (int r = 0; r < 4; r++){
      float iv = a0[r] + b2f(xv[0][r]);
      float fv = a1[r] + b2f(xv[1][r]);
      float gv = a2[r] + b2f(xv[2][r]);
      float ov = a3[r] + b2f(xv[3][r]);
      float cn = sigm(fv)*c[r] + sigm(iv)*tanh_(gv);
      c[r] = cn;
      hob[r] = f2b(sigm(ov)*tanh_(cn));
    }

    // ---- pack 4 consecutive hids into u64; publish (R6/R13-proven path) ----
    u64* dst = myslab + (size_t)(t+1)*HB_SLAB_U64;
    const int base4 = lane & 60;
#pragma unroll
    for (int r = 0; r < 4; r++){
      int hh = (int)hob[r];
      int v0 = __shfl(hh, base4+0, 64) & 0xFFFF;
      int v1 = __shfl(hh, base4+1, 64) & 0xFFFF;
      int v2 = __shfl(hh, base4+2, 64) & 0xFFFF;
      int v3 = __shfl(hh, base4+3, 64) & 0xFFFF;
      u64 v = (u64)(u32)(v0 | (v1 << 16)) | ((u64)(u32)(v2 | (v3 << 16)) << 32);
      if ((lane & 3) == 0){
        u64* d = dst + (size_t)(b0 + r)*128 + (w*4 + (n >> 2));
        __hip_atomic_store(d, v, __ATOMIC_RELAXED, __HIP_MEMORY_SCOPE_AGENT);
      }
    }
#pragma unroll
    for (int m = 0; m < 4; m++)
#pragma unroll
      for (int r = 0; r < 4; r++) xv[m][r] = xn_[m][r];
    srcp += HB_SLAB_U64 * 8;
  }
}

// ---------------- linear heads: out = h @ fc_w^T + fc_b (reads hb[t+1]) ------
__global__ __launch_bounds__(256,4) void head_fc(const u16* __restrict__ hb,
    const void* fcw0, const void* fcb0, const void* fcw1, const void* fcb1,
    void* __restrict__ dout, const int* __restrict__ flag){
  const int isb = *flag;
  const int lane = threadIdx.x & 63;
  const int wv = threadIdx.x >> 6;
  int row = blockIdx.x*4 + wv;                 // lstm*32768 + b*2048 + t
  const int lstm = row >> 15;
  const int rem = row & 32767;
  const int b = rem >> 11;
  const int t = rem & 2047;
  const u16* hrow = hb + (((size_t)lstm*2049 + (t+1))*16 + b)*512;
  float hv[8];
  {
    s16x8 h8 = *(const s16x8*)(hrow + lane*8);
#pragma unroll
    for (int e = 0; e < 8; e++) hv[e] = b2f((u16)h8[e]);
  }
  const void* fcw = lstm ? fcw1 : fcw0;
  const void* fcb = lstm ? fcb1 : fcb0;
  float bval = 0.f;
  if (lane < NOUT) bval = isb ? b2f(((const u16*)fcb)[lane]) : ((const float*)fcb)[lane];
  float res = 0.f;
  for (int o = 0; o < NOUT; o++){
    float pa = 0.f;
    if (isb){
      s16x8 w8 = *(const s16x8*)((const u16*)fcw + (size_t)o*HID + lane*8);
#pragma unroll
      for (int e = 0; e < 8; e++) pa += hv[e] * b2f((u16)w8[e]);
    } else {
      const float* wr = (const float*)fcw + (size_t)o*HID + lane*8;
#pragma unroll
      for (int e = 0; e < 8; e++) pa += hv[e] * wr[e];
    }
#pragma unroll
    for (int d = 1; d < 64; d <<= 1) pa += __shfl_xor(pa, d, 64);
    if (lane == o) res = pa + bval;
  }
  size_t off = (size_t)lstm*(MROWS*NOUT) + (size_t)rem*NOUT;
  if (lane < NOUT){
    if (isb) ((u16*)dout)[off + lane] = f2b(res);
    else     ((float*)dout)[off + lane] = res;
  }
}

extern "C" void kernel_launch(void* const* d_in, const int* in_sizes, int n_in,
                              void* d_out, int out_size, void* d_ws, size_t ws_size,
                              hipStream_t stream){
  char* ws = (char*)d_ws;
  int*   flag = (int*)(ws + WS_FLAG);
  float* bias = (float*)(ws + WS_BIAS);
  u16*   wfr  = (u16*)(ws + WS_WF);
  u16*   wb   = (u16*)(ws + WS_WB);
  u16*   xb   = (u16*)(ws + WS_XB);
  u16*   xg   = (u16*)(ws + WS_XG);
  u16*   hb   = (u16*)(ws + WS_HB);

  (void)hipMemsetAsync(ws + WS_FLAG, 0, 4096, stream);
  // sentinel-fill h history, then zero the t=0 slabs (h(0)=0)
  (void)hipMemsetAsync(ws + WS_HB, 0xFF, HB_BYTES, stream);
  (void)hipMemsetAsync(ws + WS_HB, 0, 16384, stream);
  (void)hipMemsetAsync(ws + WS_HB + 2049L*16*512*2, 0, 16384, stream);
  // sentinel-fill xg (consumed by the fused recurrence with validation)
  (void)hipMemsetAsync(ws + WS_XG, 0xFF, 268435456L, stream);

  detect_dtype<<<1, 256, 0, stream>>>((const u32*)d_in[0], flag);

  cvt_bf16<<<2048, 256, 0, stream>>>(d_in[0], xb,             67108864L/8, flag); // x
  cvt_bf16<<<2048, 256, 0, stream>>>(d_in[1], wb,              4194304L/8, flag); // w_ih
  cvt_bf16<<<2048, 256, 0, stream>>>(d_in[5], wb + 4194304L,   4194304L/8, flag); // w_ih_ed
  reorder_w<<<1024, 256, 0, stream>>>(d_in[2], d_in[6], wfr, flag);               // w_hh both
  bias_sum<<<16, 256, 0, stream>>>(d_in[3], d_in[4], d_in[7], d_in[8], bias, flag);

  fused_rec<<<64 + 8192, 256, 0, stream>>>(wfr, xb, wb, bias, xg, (u64*)hb);
  head_fc<<<16384, 256, 0, stream>>>(hb, d_in[9], d_in[10], d_in[11], d_in[12], d_out, flag);
}